// Round 12
// baseline (92.324 us; speedup 1.0000x reference)
//
#include <hip/hip_runtime.h>

#define NB 16     // batches
#define NV 19     // vertices
#define NE 361    // edges per graph
#define NL 256    // seq len
#define ND 64     // d_model
#define NTP 24    // padded tile count (exactly 6 per wave, no guards)
#define NEP (NTP * 16)  // 384 padded edges
#define ASTRIDE 136     // bf16 shorts per A row (272 B, 16B-aligned)

typedef __attribute__((ext_vector_type(8))) short bf16x8;
typedef __attribute__((ext_vector_type(4))) float f32x4;
typedef __attribute__((ext_vector_type(2))) __bf16 bf16v2;

union bf8u { unsigned u[4]; bf16x8 v; uint4 q; };

__device__ __forceinline__ unsigned pack_bf16(float lo, float hi) {
    bf16v2 v; v.x = (__bf16)lo; v.y = (__bf16)hi;   // -> v_cvt_pk_bf16_f32
    return __builtin_bit_cast(unsigned, v);
}
__device__ __forceinline__ short f2bf(float f) {
    __bf16 h = (__bf16)f;
    return __builtin_bit_cast(short, h);
}
__device__ __forceinline__ float bflo(unsigned u) {
    return __builtin_bit_cast(float, u << 16);
}
__device__ __forceinline__ float bfhi(unsigned u) {
    return __builtin_bit_cast(float, u & 0xffff0000u);
}
// packed-f32-friendly 4-wide silu: x * rcp(1 + exp2(-x*log2e))
__device__ __forceinline__ f32x4 silu4(f32x4 x) {
    f32x4 t = x * -1.44269504f;
    f32x4 d;
    d.x = __builtin_amdgcn_exp2f(t.x);
    d.y = __builtin_amdgcn_exp2f(t.y);
    d.z = __builtin_amdgcn_exp2f(t.z);
    d.w = __builtin_amdgcn_exp2f(t.w);
    d += 1.f;
    f32x4 r;
    r.x = __builtin_amdgcn_rcpf(d.x);
    r.y = __builtin_amdgcn_rcpf(d.y);
    r.z = __builtin_amdgcn_rcpf(d.z);
    r.w = __builtin_amdgcn_rcpf(d.w);
    return x * r;
}
__device__ __forceinline__ float sigm(float x) {
    return __builtin_amdgcn_rcpf(1.f + __builtin_amdgcn_exp2f(x * -1.44269504f));
}

// One block per (b, l). 256 threads = 4 waves.
// launch_bounds(256,6): 85-VGPR cap, 6 blocks/CU. r7 measured VGPR=48 under
// (256,4) which capped occupancy at 45%; 48 << 85 so no spill expected.
// (256,8)'s 64-reg cap DID spill (r9) — 85 is the safe step up.
// Spill tripwire: WRITE_SIZE must stay 5.78 MB, VGPR must stay >=48.
__global__ __launch_bounds__(256, 6) void edge_learner_kernel(
    const float* __restrict__ hs,      // (B*V, L, D)
    const float* __restrict__ ew_in,   // (B*E, L)
    const float* __restrict__ W1,      // (129, 64)
    const float* __restrict__ b1,      // (64,)
    const float* __restrict__ W2,      // (64, 32)
    const float* __restrict__ b2,      // (32,)
    const float* __restrict__ W3,      // (32, 1)
    const float* __restrict__ b3,      // (1,)
    const float* __restrict__ skip_p,  // (1,)
    const int*   __restrict__ eidx,    // (2, B*E, L)
    float* __restrict__ out)           // (B*E, L)
{
    __shared__ __align__(16) short A_s[NV * ASTRIDE];  // node projs + 0.5*b1 baked, bf16
    __shared__ __align__(16) int4  meta_s[NEP];        // {srco, tgto, ew_bits, 0}

    const int tid  = threadIdx.x;
    const int lane = tid & 63;
    const int wave = tid >> 6;
    const int lq   = lane >> 4;    // quarter (k-group)
    const int lm   = lane & 15;    // row/col within fragment
    // XCD-contiguous swizzle (4096 % 8 == 0, bijective)
    const int bid0 = blockIdx.x;
    const int bid  = (bid0 & 7) * 512 + (bid0 >> 3);
    const int b    = bid >> 8;
    const int l    = bid & 255;

    // ---------- stage edge metadata (packed int4) ----------
    for (int e = tid; e < NEP; e += 256) {
        int4 m;
        if (e < NE) {
            size_t row = (size_t)(b * NE + e) * NL + l;
            m.x = (eidx[row] % NV) * ASTRIDE;
            m.y = (eidx[(size_t)NB * NE * NL + row] % NV) * ASTRIDE + 64;
            m.z = __builtin_bit_cast(int, ew_in[row]);
            m.w = 0;
        } else {
            m.x = 0; m.y = 64; m.z = 0; m.w = 0;
        }
        meta_s[e] = m;
    }

    // ---------- per-lane constants (registers) ----------
    // layer-1 edge-weight row, channels ch(ks,i) = ks*32 + lq*8 + i  (b1 baked into A)
    f32x4 w1lv[2][2];
    #pragma unroll
    for (int ks = 0; ks < 2; ++ks) {
        w1lv[ks][0] = *(const f32x4*)&W1[128 * 64 + ks * 32 + lq * 8];
        w1lv[ks][1] = *(const f32x4*)&W1[128 * 64 + ks * 32 + lq * 8 + 4];
    }
    // W2 fragments (MFMA *A* operand = W2^T rows j = nt*16+lm)
    bf8u w2f[2][2];
    #pragma unroll
    for (int nt = 0; nt < 2; ++nt)
        #pragma unroll
        for (int ks = 0; ks < 2; ++ks) {
            const float* w2p = &W2[(ks * 32 + lq * 8) * 32 + nt * 16 + lm];
            #pragma unroll
            for (int p = 0; p < 4; ++p)
                w2f[nt][ks].u[p] = pack_bf16(w2p[(2 * p) * 32], w2p[(2 * p + 1) * 32]);
        }
    // epilogue constants: this lane's C rows j = {lq*4.., 16+lq*4..}
    const f32x4 b2v0 = *(const f32x4*)&b2[lq * 4];
    const f32x4 b2v1 = *(const f32x4*)&b2[16 + lq * 4];
    const f32x4 w3v0 = *(const f32x4*)&W3[lq * 4];
    const f32x4 w3v1 = *(const f32x4*)&W3[16 + lq * 4];
    const float b3v  = b3[0];
    const float skip = skip_p[0];

    // ---------- phase 2: A[v][c] via MFMA; wave w owns cols [32w, 32w+32) ----------
    {
        const int half = wave >> 1;
        const int oc0  = (wave & 1) * 32;
        // half of b1 baked into each A half (src cols get 0.5*b1, tgt cols 0.5*b1)
        const float hb0 = 0.5f * b1[(wave * 32 + lm) & 63];
        const float hb1 = 0.5f * b1[(wave * 32 + 16 + lm) & 63];
        bf8u w1f[2][2];   // [nt][ks]
        #pragma unroll
        for (int nt = 0; nt < 2; ++nt)
            #pragma unroll
            for (int ks = 0; ks < 2; ++ks) {
                const float* wp = &W1[(half * 64 + ks * 32 + lq * 8) * 64
                                      + oc0 + nt * 16 + lm];
                #pragma unroll
                for (int p = 0; p < 4; ++p)
                    w1f[nt][ks].u[p] = pack_bf16(wp[(2 * p) * 64], wp[(2 * p + 1) * 64]);
            }

        f32x4 acc00 = {0,0,0,0}, acc01 = {0,0,0,0}, acc10 = {0,0,0,0}, acc11 = {0,0,0,0};
        #pragma unroll
        for (int Mt = 0; Mt < 2; ++Mt) {
            int v  = Mt * 16 + lm;
            int vc = v < NV ? v : NV - 1;            // clamp pad rows
            const float* hp = hs + ((size_t)(b * NV + vc) * NL + l) * ND;
            bf8u af[2];
            #pragma unroll
            for (int ks = 0; ks < 2; ++ks) {
                float4 x0 = *(const float4*)&hp[ks * 32 + lq * 8];
                float4 x1 = *(const float4*)&hp[ks * 32 + lq * 8 + 4];
                af[ks].u[0] = pack_bf16(x0.x, x0.y);
                af[ks].u[1] = pack_bf16(x0.z, x0.w);
                af[ks].u[2] = pack_bf16(x1.x, x1.y);
                af[ks].u[3] = pack_bf16(x1.z, x1.w);
            }
            if (Mt == 0) {
                acc00 = __builtin_amdgcn_mfma_f32_16x16x32_bf16(af[0].v, w1f[0][0].v, acc00, 0, 0, 0);
                acc00 = __builtin_amdgcn_mfma_f32_16x16x32_bf16(af[1].v, w1f[0][1].v, acc00, 0, 0, 0);
                acc01 = __builtin_amdgcn_mfma_f32_16x16x32_bf16(af[0].v, w1f[1][0].v, acc01, 0, 0, 0);
                acc01 = __builtin_amdgcn_mfma_f32_16x16x32_bf16(af[1].v, w1f[1][1].v, acc01, 0, 0, 0);
            } else {
                acc10 = __builtin_amdgcn_mfma_f32_16x16x32_bf16(af[0].v, w1f[0][0].v, acc10, 0, 0, 0);
                acc10 = __builtin_amdgcn_mfma_f32_16x16x32_bf16(af[1].v, w1f[0][1].v, acc10, 0, 0, 0);
                acc11 = __builtin_amdgcn_mfma_f32_16x16x32_bf16(af[0].v, w1f[1][0].v, acc11, 0, 0, 0);
                acc11 = __builtin_amdgcn_mfma_f32_16x16x32_bf16(af[1].v, w1f[1][1].v, acc11, 0, 0, 0);
            }
        }
        // write A (bf16, +0.5*b1): row v, col c = wave*32 + {lm, 16+lm}
        #pragma unroll
        for (int r = 0; r < 4; ++r) {
            int v0 = lq * 4 + r;
            A_s[v0 * ASTRIDE + wave * 32 + lm]      = f2bf(acc00[r] + hb0);
            A_s[v0 * ASTRIDE + wave * 32 + 16 + lm] = f2bf(acc01[r] + hb1);
            int v1 = 16 + lq * 4 + r;
            if (v1 < NV) {
                A_s[v1 * ASTRIDE + wave * 32 + lm]      = f2bf(acc10[r] + hb0);
                A_s[v1 * ASTRIDE + wave * 32 + 16 + lm] = f2bf(acc11[r] + hb1);
            }
        }
    }
    __syncthreads();

    // ---------- phase 3: 6 tiles/wave, 1-ahead software pipeline ----------
    int4 mA = meta_s[wave * 16 + lm];
    uint4 gs0 = *(const uint4*)&A_s[mA.x + lq * 8];
    uint4 gs1 = *(const uint4*)&A_s[mA.x + 32 + lq * 8];
    uint4 gt0 = *(const uint4*)&A_s[mA.y + lq * 8];
    uint4 gt1 = *(const uint4*)&A_s[mA.y + 32 + lq * 8];

    #pragma unroll
    for (int i = 0; i < 6; ++i) {
        const int t  = wave + 4 * i;
        const float ew = __builtin_bit_cast(float, mA.z);

        // early: next tile's meta (latency hidden under this tile's compute)
        int4 mB = mA;
        if (i < 5) mB = meta_s[(t + 4) * 16 + lm];

        // layer 1: unpack current gathers, packed math, silu, repack bf16
        bf8u a1[2];
        #pragma unroll
        for (int ks = 0; ks < 2; ++ks) {
            const uint4 as = ks ? gs1 : gs0;
            const uint4 at = ks ? gt1 : gt0;
            f32x4 x0, x1;
            x0.x = bflo(as.x) + bflo(at.x);
            x0.y = bfhi(as.x) + bfhi(at.x);
            x0.z = bflo(as.y) + bflo(at.y);
            x0.w = bfhi(as.y) + bfhi(at.y);
            x1.x = bflo(as.z) + bflo(at.z);
            x1.y = bfhi(as.z) + bfhi(at.z);
            x1.z = bflo(as.w) + bflo(at.w);
            x1.w = bfhi(as.w) + bfhi(at.w);
            x0 += ew * w1lv[ks][0];
            x1 += ew * w1lv[ks][1];
            f32x4 y0 = silu4(x0);
            f32x4 y1 = silu4(x1);
            a1[ks].u[0] = pack_bf16(y0.x, y0.y);
            a1[ks].u[1] = pack_bf16(y0.z, y0.w);
            a1[ks].u[2] = pack_bf16(y1.x, y1.y);
            a1[ks].u[3] = pack_bf16(y1.z, y1.w);
        }

        // layer 2: W2^T @ h1^T -> C[row=j, col=edge]  (4 MFMAs)
        f32x4 c0 = {0,0,0,0}, c1 = {0,0,0,0};
        c0 = __builtin_amdgcn_mfma_f32_16x16x32_bf16(w2f[0][0].v, a1[0].v, c0, 0, 0, 0);
        c0 = __builtin_amdgcn_mfma_f32_16x16x32_bf16(w2f[0][1].v, a1[1].v, c0, 0, 0, 0);
        c1 = __builtin_amdgcn_mfma_f32_16x16x32_bf16(w2f[1][0].v, a1[0].v, c1, 0, 0, 0);
        c1 = __builtin_amdgcn_mfma_f32_16x16x32_bf16(w2f[1][1].v, a1[1].v, c1, 0, 0, 0);

        // issue NEXT tile's gathers now — latency hides under the epilogue
        uint4 ns0 = gs0, ns1 = gs1, nt0 = gt0, nt1 = gt1;
        if (i < 5) {
            ns0 = *(const uint4*)&A_s[mB.x + lq * 8];
            ns1 = *(const uint4*)&A_s[mB.x + 32 + lq * 8];
            nt0 = *(const uint4*)&A_s[mB.y + lq * 8];
            nt1 = *(const uint4*)&A_s[mB.y + 32 + lq * 8];
        }

        // epilogue: silu over this lane's 8 j-rows (col = edge lm),
        // local dot with W3, 2-shuffle reduce over lq groups
        f32x4 h0 = silu4(c0 + b2v0);
        f32x4 h1 = silu4(c1 + b2v1);
        f32x4 pv = h0 * w3v0 + h1 * w3v1;
        float p  = (pv.x + pv.y) + (pv.z + pv.w);
        p += __shfl_xor(p, 16);
        p += __shfl_xor(p, 32);

        if (lane < 16) {
            int er = t * 16 + lane;
            if (er < NE) {
                float wgt = sigm(p + b3v);
                out[(size_t)(b * NE + er) * NL + l] = skip * ew + (1.f - skip) * wgt;
            }
        }

        // rotate pipeline registers (renamed by full unroll)
        mA = mB;
        gs0 = ns0; gs1 = ns1; gt0 = nt0; gt1 = nt1;
    }
}

extern "C" void kernel_launch(void* const* d_in, const int* in_sizes, int n_in,
                              void* d_out, int out_size, void* d_ws, size_t ws_size,
                              hipStream_t stream) {
    const float* hs   = (const float*)d_in[0];
    const float* ew   = (const float*)d_in[1];
    const float* W1   = (const float*)d_in[2];
    const float* b1   = (const float*)d_in[3];
    const float* W2   = (const float*)d_in[4];
    const float* b2   = (const float*)d_in[5];
    const float* W3   = (const float*)d_in[6];
    const float* b3   = (const float*)d_in[7];
    const float* skip = (const float*)d_in[8];
    const int*   eidx = (const int*)d_in[9];
    float* outp = (float*)d_out;

    dim3 grid(NB * NL);   // 4096 blocks, one per (b, l)
    dim3 block(256);
    hipLaunchKernelGGL(edge_learner_kernel, grid, block, 0, stream,
                       hs, ew, W1, b1, W2, b2, W3, b3, skip, eidx, outp);
}

// Round 13
// 57.226 us; speedup vs baseline: 1.6133x; 1.6133x over previous
//
#include <hip/hip_runtime.h>

#define NB 16     // batches
#define NV 19     // vertices
#define NE 361    // edges per graph
#define NL 256    // seq len
#define ND 64     // d_model
#define NTP 24    // padded tile count (exactly 6 per wave, no guards)
#define NEP (NTP * 16)  // 384 padded edges
#define ASTRIDE 136     // bf16 shorts per A row (272 B, 16B-aligned)

typedef __attribute__((ext_vector_type(8))) short bf16x8;
typedef __attribute__((ext_vector_type(4))) float f32x4;
typedef __attribute__((ext_vector_type(2))) __bf16 bf16v2;

union bf8u { unsigned u[4]; bf16x8 v; uint4 q; };

__device__ __forceinline__ unsigned pack_bf16(float lo, float hi) {
    bf16v2 v; v.x = (__bf16)lo; v.y = (__bf16)hi;   // -> v_cvt_pk_bf16_f32
    return __builtin_bit_cast(unsigned, v);
}
__device__ __forceinline__ short f2bf(float f) {
    __bf16 h = (__bf16)f;
    return __builtin_bit_cast(short, h);
}
__device__ __forceinline__ float bflo(unsigned u) {
    return __builtin_bit_cast(float, u << 16);
}
__device__ __forceinline__ float bfhi(unsigned u) {
    return __builtin_bit_cast(float, u & 0xffff0000u);
}
// packed-f32-friendly 4-wide silu: x * rcp(1 + exp2(-x*log2e))
__device__ __forceinline__ f32x4 silu4(f32x4 x) {
    f32x4 t = x * -1.44269504f;
    f32x4 d;
    d.x = __builtin_amdgcn_exp2f(t.x);
    d.y = __builtin_amdgcn_exp2f(t.y);
    d.z = __builtin_amdgcn_exp2f(t.z);
    d.w = __builtin_amdgcn_exp2f(t.w);
    d += 1.f;
    f32x4 r;
    r.x = __builtin_amdgcn_rcpf(d.x);
    r.y = __builtin_amdgcn_rcpf(d.y);
    r.z = __builtin_amdgcn_rcpf(d.z);
    r.w = __builtin_amdgcn_rcpf(d.w);
    return x * r;
}
__device__ __forceinline__ float sigm(float x) {
    return __builtin_amdgcn_rcpf(1.f + __builtin_amdgcn_exp2f(x * -1.44269504f));
}

// One block per (b, l). 256 threads = 4 waves.
// launch_bounds(256,5): ~96-102 unified-VGPR cap, 5 blocks/CU.
// Register-pressure history: unified demand ~88 with pipeline; (256,6)=85 cap
// barely spilled (r12, WRITE 84MB), (256,8)=64 spilled badly (r9, 205MB).
// This round: pipeline removed + uint2 meta (-~16 regs demand) + cap 96.
// Spill tripwire: WRITE_SIZE must stay 5.78 MB.
__global__ __launch_bounds__(256, 5) void edge_learner_kernel(
    const float* __restrict__ hs,      // (B*V, L, D)
    const float* __restrict__ ew_in,   // (B*E, L)
    const float* __restrict__ W1,      // (129, 64)
    const float* __restrict__ b1,      // (64,)
    const float* __restrict__ W2,      // (64, 32)
    const float* __restrict__ b2,      // (32,)
    const float* __restrict__ W3,      // (32, 1)
    const float* __restrict__ b3,      // (1,)
    const float* __restrict__ skip_p,  // (1,)
    const int*   __restrict__ eidx,    // (2, B*E, L)
    float* __restrict__ out)           // (B*E, L)
{
    __shared__ __align__(16) short A_s[NV * ASTRIDE];  // node projs + 0.5*b1 baked, bf16
    __shared__ __align__(8)  uint2 meta_s[NEP];        // {src|tgt<<16, ew_bits}

    const int tid  = threadIdx.x;
    const int lane = tid & 63;
    const int wave = tid >> 6;
    const int lq   = lane >> 4;    // quarter (k-group)
    const int lm   = lane & 15;    // row/col within fragment
    // XCD-contiguous swizzle (4096 % 8 == 0, bijective)
    const int bid0 = blockIdx.x;
    const int bid  = (bid0 & 7) * 512 + (bid0 >> 3);
    const int b    = bid >> 8;
    const int l    = bid & 255;

    // ---------- stage edge metadata (8 B/edge) ----------
    for (int e = tid; e < NEP; e += 256) {
        uint2 m;
        if (e < NE) {
            size_t row = (size_t)(b * NE + e) * NL + l;
            unsigned so = (unsigned)((eidx[row] % NV) * ASTRIDE);
            unsigned to = (unsigned)((eidx[(size_t)NB * NE * NL + row] % NV) * ASTRIDE + 64);
            m.x = so | (to << 16);
            m.y = __builtin_bit_cast(unsigned, ew_in[row]);
        } else {
            m.x = 64u << 16; m.y = 0u;
        }
        meta_s[e] = m;
    }

    // ---------- per-lane constants (registers) ----------
    // layer-1 edge-weight row, channels ch(ks,i) = ks*32 + lq*8 + i  (b1 baked into A)
    f32x4 w1lv[2][2];
    #pragma unroll
    for (int ks = 0; ks < 2; ++ks) {
        w1lv[ks][0] = *(const f32x4*)&W1[128 * 64 + ks * 32 + lq * 8];
        w1lv[ks][1] = *(const f32x4*)&W1[128 * 64 + ks * 32 + lq * 8 + 4];
    }
    // W2 fragments (MFMA *A* operand = W2^T rows j = nt*16+lm)
    bf8u w2f[2][2];
    #pragma unroll
    for (int nt = 0; nt < 2; ++nt)
        #pragma unroll
        for (int ks = 0; ks < 2; ++ks) {
            const float* w2p = &W2[(ks * 32 + lq * 8) * 32 + nt * 16 + lm];
            #pragma unroll
            for (int p = 0; p < 4; ++p)
                w2f[nt][ks].u[p] = pack_bf16(w2p[(2 * p) * 32], w2p[(2 * p + 1) * 32]);
        }
    // epilogue constants: this lane's C rows j = {lq*4.., 16+lq*4..}
    const f32x4 b2v0 = *(const f32x4*)&b2[lq * 4];
    const f32x4 b2v1 = *(const f32x4*)&b2[16 + lq * 4];
    const f32x4 w3v0 = *(const f32x4*)&W3[lq * 4];
    const f32x4 w3v1 = *(const f32x4*)&W3[16 + lq * 4];
    const float b3v  = b3[0];
    const float skip = skip_p[0];

    // ---------- phase 2: A[v][c] via MFMA; wave w owns cols [32w, 32w+32) ----------
    {
        const int half = wave >> 1;
        const int oc0  = (wave & 1) * 32;
        // half of b1 baked into each A half (src cols get 0.5*b1, tgt cols 0.5*b1)
        const float hb0 = 0.5f * b1[(wave * 32 + lm) & 63];
        const float hb1 = 0.5f * b1[(wave * 32 + 16 + lm) & 63];
        bf8u w1f[2][2];   // [nt][ks]
        #pragma unroll
        for (int nt = 0; nt < 2; ++nt)
            #pragma unroll
            for (int ks = 0; ks < 2; ++ks) {
                const float* wp = &W1[(half * 64 + ks * 32 + lq * 8) * 64
                                      + oc0 + nt * 16 + lm];
                #pragma unroll
                for (int p = 0; p < 4; ++p)
                    w1f[nt][ks].u[p] = pack_bf16(wp[(2 * p) * 64], wp[(2 * p + 1) * 64]);
            }

        f32x4 acc00 = {0,0,0,0}, acc01 = {0,0,0,0}, acc10 = {0,0,0,0}, acc11 = {0,0,0,0};
        #pragma unroll
        for (int Mt = 0; Mt < 2; ++Mt) {
            int v  = Mt * 16 + lm;
            int vc = v < NV ? v : NV - 1;            // clamp pad rows
            const float* hp = hs + ((size_t)(b * NV + vc) * NL + l) * ND;
            bf8u af[2];
            #pragma unroll
            for (int ks = 0; ks < 2; ++ks) {
                float4 x0 = *(const float4*)&hp[ks * 32 + lq * 8];
                float4 x1 = *(const float4*)&hp[ks * 32 + lq * 8 + 4];
                af[ks].u[0] = pack_bf16(x0.x, x0.y);
                af[ks].u[1] = pack_bf16(x0.z, x0.w);
                af[ks].u[2] = pack_bf16(x1.x, x1.y);
                af[ks].u[3] = pack_bf16(x1.z, x1.w);
            }
            if (Mt == 0) {
                acc00 = __builtin_amdgcn_mfma_f32_16x16x32_bf16(af[0].v, w1f[0][0].v, acc00, 0, 0, 0);
                acc00 = __builtin_amdgcn_mfma_f32_16x16x32_bf16(af[1].v, w1f[0][1].v, acc00, 0, 0, 0);
                acc01 = __builtin_amdgcn_mfma_f32_16x16x32_bf16(af[0].v, w1f[1][0].v, acc01, 0, 0, 0);
                acc01 = __builtin_amdgcn_mfma_f32_16x16x32_bf16(af[1].v, w1f[1][1].v, acc01, 0, 0, 0);
            } else {
                acc10 = __builtin_amdgcn_mfma_f32_16x16x32_bf16(af[0].v, w1f[0][0].v, acc10, 0, 0, 0);
                acc10 = __builtin_amdgcn_mfma_f32_16x16x32_bf16(af[1].v, w1f[0][1].v, acc10, 0, 0, 0);
                acc11 = __builtin_amdgcn_mfma_f32_16x16x32_bf16(af[0].v, w1f[1][0].v, acc11, 0, 0, 0);
                acc11 = __builtin_amdgcn_mfma_f32_16x16x32_bf16(af[1].v, w1f[1][1].v, acc11, 0, 0, 0);
            }
        }
        // write A (bf16, +0.5*b1): row v, col c = wave*32 + {lm, 16+lm}
        #pragma unroll
        for (int r = 0; r < 4; ++r) {
            int v0 = lq * 4 + r;
            A_s[v0 * ASTRIDE + wave * 32 + lm]      = f2bf(acc00[r] + hb0);
            A_s[v0 * ASTRIDE + wave * 32 + 16 + lm] = f2bf(acc01[r] + hb1);
            int v1 = 16 + lq * 4 + r;
            if (v1 < NV) {
                A_s[v1 * ASTRIDE + wave * 32 + lm]      = f2bf(acc10[r] + hb0);
                A_s[v1 * ASTRIDE + wave * 32 + 16 + lm] = f2bf(acc11[r] + hb1);
            }
        }
    }
    __syncthreads();

    // ---------- phase 3: 6 tiles/wave, plain loop (pipeline removed: r6 vs r7
    // showed it neutral, and its register set pushed demand over the spill edge) ----------
    #pragma unroll
    for (int i = 0; i < 6; ++i) {
        const int t = wave + 4 * i;
        const uint2 m = meta_s[t * 16 + lm];
        const int so = (int)(m.x & 0xffffu);
        const int to = (int)(m.x >> 16);
        const float ew = __builtin_bit_cast(float, m.y);

        // layer 1: bf16 gathers, pairwise unpack, packed math, silu, repack
        bf8u a1[2];
        #pragma unroll
        for (int ks = 0; ks < 2; ++ks) {
            const uint4 as = *(const uint4*)&A_s[so + ks * 32 + lq * 8];
            const uint4 at = *(const uint4*)&A_s[to + ks * 32 + lq * 8];
            f32x4 x0, x1;
            x0.x = bflo(as.x) + bflo(at.x);
            x0.y = bfhi(as.x) + bfhi(at.x);
            x0.z = bflo(as.y) + bflo(at.y);
            x0.w = bfhi(as.y) + bfhi(at.y);
            x1.x = bflo(as.z) + bflo(at.z);
            x1.y = bfhi(as.z) + bfhi(at.z);
            x1.z = bflo(as.w) + bflo(at.w);
            x1.w = bfhi(as.w) + bfhi(at.w);
            x0 += ew * w1lv[ks][0];
            x1 += ew * w1lv[ks][1];
            f32x4 y0 = silu4(x0);
            f32x4 y1 = silu4(x1);
            a1[ks].u[0] = pack_bf16(y0.x, y0.y);
            a1[ks].u[1] = pack_bf16(y0.z, y0.w);
            a1[ks].u[2] = pack_bf16(y1.x, y1.y);
            a1[ks].u[3] = pack_bf16(y1.z, y1.w);
        }

        // layer 2: W2^T @ h1^T -> C[row=j, col=edge]  (4 MFMAs)
        f32x4 c0 = {0,0,0,0}, c1 = {0,0,0,0};
        c0 = __builtin_amdgcn_mfma_f32_16x16x32_bf16(w2f[0][0].v, a1[0].v, c0, 0, 0, 0);
        c0 = __builtin_amdgcn_mfma_f32_16x16x32_bf16(w2f[0][1].v, a1[1].v, c0, 0, 0, 0);
        c1 = __builtin_amdgcn_mfma_f32_16x16x32_bf16(w2f[1][0].v, a1[0].v, c1, 0, 0, 0);
        c1 = __builtin_amdgcn_mfma_f32_16x16x32_bf16(w2f[1][1].v, a1[1].v, c1, 0, 0, 0);

        // epilogue: silu over this lane's 8 j-rows (col = edge lm),
        // local dot with W3, 2-shuffle reduce over lq groups
        f32x4 h0 = silu4(c0 + b2v0);
        f32x4 h1 = silu4(c1 + b2v1);
        f32x4 pv = h0 * w3v0 + h1 * w3v1;
        float p  = (pv.x + pv.y) + (pv.z + pv.w);
        p += __shfl_xor(p, 16);
        p += __shfl_xor(p, 32);

        if (lane < 16) {
            int er = t * 16 + lane;
            if (er < NE) {
                float wgt = sigm(p + b3v);
                out[(size_t)(b * NE + er) * NL + l] = skip * ew + (1.f - skip) * wgt;
            }
        }
    }
}

extern "C" void kernel_launch(void* const* d_in, const int* in_sizes, int n_in,
                              void* d_out, int out_size, void* d_ws, size_t ws_size,
                              hipStream_t stream) {
    const float* hs   = (const float*)d_in[0];
    const float* ew   = (const float*)d_in[1];
    const float* W1   = (const float*)d_in[2];
    const float* b1   = (const float*)d_in[3];
    const float* W2   = (const float*)d_in[4];
    const float* b2   = (const float*)d_in[5];
    const float* W3   = (const float*)d_in[6];
    const float* b3   = (const float*)d_in[7];
    const float* skip = (const float*)d_in[8];
    const int*   eidx = (const int*)d_in[9];
    float* outp = (float*)d_out;

    dim3 grid(NB * NL);   // 4096 blocks, one per (b, l)
    dim3 block(256);
    hipLaunchKernelGGL(edge_learner_kernel, grid, block, 0, stream,
                       hs, ew, W1, b1, W2, b2, W3, b3, skip, eidx, outp);
}